// Round 4
// baseline (1482.611 us; speedup 1.0000x reference)
//
#include <hip/hip_runtime.h>
#include <math.h>

#define NPERM 24
#define ND 256
#define RPB 48            // rows per block (one batch elem per block)
#define RPW 12            // rows per wave (4 waves)
#define ROWS_PER_B 576
#define BATCH 512
#define NBLOCKS (BATCH * ROWS_PER_B / RPB)   // 6144

// itertools.permutations(range(4)) — lexicographic order, with parity signs
__constant__ int c_P[NPERM * 4] = {
    0,1,2,3, 0,1,3,2, 0,2,1,3, 0,2,3,1, 0,3,1,2, 0,3,2,1,
    1,0,2,3, 1,0,3,2, 1,2,0,3, 1,2,3,0, 1,3,0,2, 1,3,2,0,
    2,0,1,3, 2,0,3,1, 2,1,0,3, 2,1,3,0, 2,3,0,1, 2,3,1,0,
    3,0,1,2, 3,0,2,1, 3,1,0,2, 3,1,2,0, 3,2,0,1, 3,2,1,0
};
__constant__ float c_S[NPERM] = {
     1.f,-1.f,-1.f, 1.f, 1.f,-1.f,
    -1.f, 1.f, 1.f,-1.f,-1.f, 1.f,
     1.f,-1.f,-1.f, 1.f, 1.f,-1.f,
    -1.f, 1.f, 1.f,-1.f,-1.f, 1.f
};

// async global->LDS DMA, 16B per lane; LDS dest = wave-uniform base + lane*16
__device__ __forceinline__ void gl_lds16(const float* g, float* l) {
    __builtin_amdgcn_global_load_lds(
        (const __attribute__((address_space(1))) void*)g,
        (__attribute__((address_space(3)))  void*)l, 16, 0, 0);
}

__global__ __launch_bounds__(256, 2)
void fused_resnet(const float* __restrict__ x1, const float* __restrict__ x2,
                  const float* __restrict__ W0, const float* __restrict__ b0,
                  const float* __restrict__ W1, const float* __restrict__ b1,
                  const float* __restrict__ W2, const float* __restrict__ b2,
                  const float* __restrict__ Wf, const float* __restrict__ bf,
                  double* __restrict__ anti)
{
    __shared__ float sY[RPB * ND];   // 48 KB activations (wave-private row bands)
    __shared__ float sW[8192];       // 32 KB: two 16 KB ping-pong W buffers
                                     // layer0: buf0 = W0 tiles (2 halves), buf1[0..1151] = feats
    const int t   = threadIdx.x;
    const int tc  = t & 63;          // col group: cols 4*tc..4*tc+3
    const int tr  = t >> 6;          // wave id: rows 12*tr..12*tr+11
    const int gr0 = blockIdx.x * RPB;
    const int b   = gr0 / ROWS_PER_B;

    // prefetch W0 tile0 (rows 0..7 = 2048 floats) into buf0 lower half (8 chunks, 2/wave)
    #pragma unroll
    for (int i = 0; i < 2; ++i) {
        int c = tr * 2 + i;
        gl_lds16(W0 + c * 256 + tc * 4, &sW[c * 256]);
    }

    // ---- build features into sW[4096 + lr*24 + c] ----
    for (int e = t; e < RPB * 24; e += 256) {
        int lr = e / 24, c = e % 24;
        int pp = (gr0 + lr) % ROWS_PER_B;
        float v;
        if (c < 12) {
            int p1 = pp / 24;
            v = x1[b * 12 + c_P[p1 * 4 + c / 3] * 3 + (c % 3)];
        } else {
            int p2 = pp % 24; int cc = c - 12;
            v = x2[b * 12 + c_P[p2 * 4 + cc / 3] * 3 + (cc % 3)];
        }
        sW[4096 + e] = v;
    }

    float acc[RPW][4];   // fp32 accumulators, single sequential chain over K (np order)

    // ---------- layer 0: 24 -> 256, tanh, no residual ----------
    #pragma unroll
    for (int r = 0; r < RPW; ++r) { acc[r][0]=0.f; acc[r][1]=0.f; acc[r][2]=0.f; acc[r][3]=0.f; }
    for (int kt3 = 0; kt3 < 3; ++kt3) {
        __syncthreads();   // tile kt3 DMA complete (vmcnt drain) + feats visible
        if (kt3 < 2) {     // prefetch next 8-row tile into the other half of buf0
            const float* src = W0 + (kt3 + 1) * 2048;
            float* dst = &sW[((kt3 + 1) & 1) * 2048];
            #pragma unroll
            for (int i = 0; i < 2; ++i) {
                int c = tr * 2 + i;
                gl_lds16(src + c * 256 + tc * 4, dst + c * 256);
            }
        }
        const float* wt = &sW[(kt3 & 1) * 2048];
        #pragma unroll
        for (int k4 = 0; k4 < 2; ++k4) {
            float w[4][4];
            #pragma unroll
            for (int k = 0; k < 4; ++k) {
                float4 wv = *(const float4*)&wt[(k4 * 4 + k) * 256 + 4 * tc];
                w[k][0]=wv.x; w[k][1]=wv.y; w[k][2]=wv.z; w[k][3]=wv.w;
            }
            #pragma unroll
            for (int r = 0; r < RPW; ++r) {
                float4 yv = *(const float4*)&sW[4096 + (tr * RPW + r) * 24 + kt3 * 8 + k4 * 4];
                float yk[4] = {yv.x, yv.y, yv.z, yv.w};
                #pragma unroll
                for (int k = 0; k < 4; ++k)
                    #pragma unroll
                    for (int c = 0; c < 4; ++c)
                        acc[r][c] = fmaf(yk[k], w[k][c], acc[r][c]);
            }
        }
    }
    __syncthreads();   // all waves done with feats (buf1) and buf0
    // prefetch W1 tile0 -> buf1 (16 chunks of 256 floats, 4/wave)
    #pragma unroll
    for (int i = 0; i < 4; ++i) {
        int c = tr * 4 + i;
        gl_lds16(W1 + c * 256 + tc * 4, &sW[4096 + c * 256]);
    }
    {   // layer-0 epilogue: bias + tanh -> sY (wave-private rows, no barrier needed)
        float4 bv = *(const float4*)&b0[4 * tc];
        float bb[4] = {bv.x, bv.y, bv.z, bv.w};
        #pragma unroll
        for (int r = 0; r < RPW; ++r) {
            float4 o;
            o.x = tanhf(acc[r][0] + bb[0]);
            o.y = tanhf(acc[r][1] + bb[1]);
            o.z = tanhf(acc[r][2] + bb[2]);
            o.w = tanhf(acc[r][3] + bb[3]);
            *(float4*)&sY[(tr * RPW + r) * ND + 4 * tc] = o;
        }
    }

    // ---------- layers 1,2: 256 -> 256, tanh + residual; prefetched ping-pong ----------
    int cur = 1;   // W1 tile0 lands in buf1
    #pragma unroll 1
    for (int layer = 0; layer < 2; ++layer) {
        const float* Wcur = layer ? W2 : W1;
        const float* bcur = layer ? b2 : b1;
        #pragma unroll
        for (int r = 0; r < RPW; ++r) { acc[r][0]=0.f; acc[r][1]=0.f; acc[r][2]=0.f; acc[r][3]=0.f; }
        #pragma unroll 1
        for (int ktile = 0; ktile < 16; ++ktile) {
            __syncthreads();   // buf[cur] DMA complete; everyone done reading buf[1-cur]
            float* nb = &sW[(1 - cur) * 4096];
            if (ktile < 15) {          // prefetch next tile of this layer
                const float* src = Wcur + (ktile + 1) * 4096;
                #pragma unroll
                for (int i = 0; i < 4; ++i) {
                    int c = tr * 4 + i;
                    gl_lds16(src + c * 256 + tc * 4, nb + c * 256);
                }
            } else if (layer == 0) {   // prefetch W2 tile0
                #pragma unroll
                for (int i = 0; i < 4; ++i) {
                    int c = tr * 4 + i;
                    gl_lds16(W2 + c * 256 + tc * 4, nb + c * 256);
                }
            } else {                   // prefetch Wf, one private 1 KB copy per wave
                gl_lds16(Wf + tc * 4, nb + tr * 256);
            }
            const float* wt = &sW[cur * 4096];
            #pragma unroll
            for (int k4 = 0; k4 < 4; ++k4) {
                float w[4][4];
                #pragma unroll
                for (int k = 0; k < 4; ++k) {
                    float4 wv = *(const float4*)&wt[(k4 * 4 + k) * 256 + 4 * tc];
                    w[k][0]=wv.x; w[k][1]=wv.y; w[k][2]=wv.z; w[k][3]=wv.w;
                }
                #pragma unroll
                for (int r = 0; r < RPW; ++r) {
                    float4 yv = *(const float4*)&sY[(tr * RPW + r) * ND + ktile * 16 + k4 * 4];
                    float yk[4] = {yv.x, yv.y, yv.z, yv.w};
                    #pragma unroll
                    for (int k = 0; k < 4; ++k)
                        #pragma unroll
                        for (int c = 0; c < 4; ++c)
                            acc[r][c] = fmaf(yk[k], w[k][c], acc[r][c]);
                }
            }
            cur ^= 1;
        }
        // epilogue: bias + tanh + residual (wave-private rows -> no barriers)
        float4 bv = *(const float4*)&bcur[4 * tc];
        float bb[4] = {bv.x, bv.y, bv.z, bv.w};
        #pragma unroll
        for (int r = 0; r < RPW; ++r) {
            float4 yo = *(const float4*)&sY[(tr * RPW + r) * ND + 4 * tc];
            float4 o;
            o.x = tanhf(acc[r][0] + bb[0]) + yo.x;
            o.y = tanhf(acc[r][1] + bb[1]) + yo.y;
            o.z = tanhf(acc[r][2] + bb[2]) + yo.z;
            o.w = tanhf(acc[r][3] + bb[3]) + yo.w;
            *(float4*)&sY[(tr * RPW + r) * ND + 4 * tc] = o;
        }
    }

    // ---------- head ----------
    // After the loops cur==1, so Wf landed in buf1 at sW[4096 + tr*256].
    __syncthreads();   // drain Wf DMA
    double contrib = 0.0;
    if (tc < RPW) {
        int row = tr * RPW + tc;
        const float* yrow = &sY[row * ND];
        const float* wfp  = &sW[4096 + tr * 256];   // broadcast within wave (free)
        float f = 0.f;
        #pragma unroll 8
        for (int k = 0; k < ND; ++k) f = fmaf(yrow[k], wfp[k], f);
        f += bf[0];
        int pp = (gr0 + row) % ROWS_PER_B;
        double s = (double)(c_S[pp / 24] * c_S[pp % 24]);
        contrib = s * (double)f;
    }
    #pragma unroll
    for (int off = 32; off > 0; off >>= 1) contrib += __shfl_xor(contrib, off, 64);
    if (tc == 0) atomicAdd(&anti[b], contrib);
}

__global__ void finalize_log(const double* __restrict__ anti, float* __restrict__ out) {
    int i = blockIdx.x * 256 + threadIdx.x;
    if (i < BATCH) out[i] = (float)log(fabs(anti[i]));
}

extern "C" void kernel_launch(void* const* d_in, const int* in_sizes, int n_in,
                              void* d_out, int out_size, void* d_ws, size_t ws_size,
                              hipStream_t stream) {
    const float* x1 = (const float*)d_in[0];
    const float* x2 = (const float*)d_in[1];
    const float* W0 = (const float*)d_in[2];
    const float* b0 = (const float*)d_in[3];
    const float* W1 = (const float*)d_in[4];
    const float* b1 = (const float*)d_in[5];
    const float* W2 = (const float*)d_in[6];
    const float* b2 = (const float*)d_in[7];
    const float* Wf = (const float*)d_in[8];
    const float* bf = (const float*)d_in[9];
    double* anti = (double*)d_ws;                   // 512 doubles of scratch
    float* out   = (float*)d_out;

    hipMemsetAsync(anti, 0, BATCH * sizeof(double), stream);
    fused_resnet<<<NBLOCKS, 256, 0, stream>>>(x1, x2, W0, b0, W1, b1, W2, b2, Wf, bf, anti);
    finalize_log<<<(BATCH + 255) / 256, 256, 0, stream>>>(anti, out);
}